// Round 15
// baseline (130.279 us; speedup 1.0000x reference)
//
#include <hip/hip_runtime.h>
#include <hip/hip_bf16.h>
#include <cstdint>

#define Bc 2
#define Nc 3072
#define Hc 4
#define NW32 96      // 32-key subtiles per row
#define KSC 8        // key splits
#define TPS (NW32/KSC)   // 12 subtiles per split

typedef __bf16    bf16x8 __attribute__((ext_vector_type(8)));
typedef _Float16  f16x8  __attribute__((ext_vector_type(8)));
typedef float     f32x16 __attribute__((ext_vector_type(16)));

#define QSCALE 0.18033688f   // 0.125 * log2(e): exp(s/8) == exp2(s*QSCALE)

static __device__ __forceinline__ f32x16 mfma32bf(bf16x8 a, bf16x8 b, f32x16 c) {
    return __builtin_amdgcn_mfma_f32_32x32x16_bf16(a, b, c, 0, 0, 0);
}
static __device__ __forceinline__ f32x16 mfma32h(f16x8 a, f16x8 b, f32x16 c) {
    return __builtin_amdgcn_mfma_f32_32x32x16_f16(a, b, c, 0, 0, 0);
}
static __device__ __forceinline__ uint32_t pkrtz(float lo, float hi) {
    uint32_t w;
    asm("v_cvt_pkrtz_f16_f32 %0, %1, %2" : "=v"(w) : "v"(lo), "v"(hi));
    return w;
}

// softmax for one 32-key subtile (16 scores/lane): leaky+exp2, pack to fp16,
// mask the PACKED word, denominator via v_dot2 on the same masked packed values
static __device__ __forceinline__ void softmax_pack(const f32x16& sc, uint32_t mwh,
                                                    uint32_t W8[8], float& lsum,
                                                    uint32_t ones32)
{
    #pragma unroll
    for (int i = 0; i < 8; ++i) {
        const int bp0 = (2*i & 3) + 8*(2*i >> 2);   // bp1 = bp0+1
        float s0 = sc[2*i], s1 = sc[2*i + 1];
        float a0 = fmaxf(s0, 0.2f*s0);
        float a1 = fmaxf(s1, 0.2f*s1);
        float e0, e1;
        asm("v_exp_f32 %0, %1" : "=v"(e0) : "v"(a0));   // exp2 (log2e pre-folded)
        asm("v_exp_f32 %0, %1" : "=v"(e1) : "v"(a1));
        uint32_t pk = pkrtz(e0, e1);
        uint32_t m0 = (uint32_t)(((int)(mwh << (31 - bp0))) >> 31);
        uint32_t m1 = (uint32_t)(((int)(mwh << (30 - bp0))) >> 31);
        uint32_t wv = pk & ((m0 & 0x0000ffffu) | (m1 & 0xffff0000u));
        W8[i] = wv;
        asm("v_dot2_f32_f16 %0, %1, %2, %0" : "+v"(lsum) : "v"(wv), "v"(ones32));
    }
}

static __device__ __forceinline__ void assemble_pa(uint32_t W8[8], f16x8& pa0, f16x8& pa1)
{
    uint32_t a0 = W8[0], a2 = W8[2], a1 = W8[1], a3 = W8[3];
    uint32_t b0 = W8[4], b2 = W8[6], b1 = W8[5], b3 = W8[7];
    asm("v_permlane32_swap_b32 %0, %1" : "+v"(a0), "+v"(a2));
    asm("v_permlane32_swap_b32 %0, %1" : "+v"(a1), "+v"(a3));
    asm("v_permlane32_swap_b32 %0, %1" : "+v"(b0), "+v"(b2));
    asm("v_permlane32_swap_b32 %0, %1" : "+v"(b1), "+v"(b3));
    union { uint32_t u[4]; f16x8 v; } u0, u1;
    u0.u[0] = a0; u0.u[1] = a1; u0.u[2] = a2; u0.u[3] = a3;
    u1.u[0] = b0; u1.u[1] = b1; u1.u[2] = b2; u1.u[3] = b3;
    pa0 = u0.v; pa1 = u1.v;
}

// load one subtile's K (flat Kf) and V (Vimg granules) fragments into registers
static __device__ __forceinline__ void load_subtile(const char* gk, const char* gv,
                                                    int hi, int l31,
                                                    f16x8 (&K)[4], f16x8 (&V)[4])
{
    #pragma unroll
    for (int kk = 0; kk < 4; ++kk)
        K[kk] = *(const f16x8*)(gk + ((kk*2 + hi) << 4));
    #pragma unroll
    for (int i = 0; i < 4; ++i) {
        const int kkp = i >> 1, ot = i & 1;
        V[i] = *(const f16x8*)(gv + ((kkp*2 + hi) << 10) + ((ot*32 + l31) << 4));
    }
}

// full compute for one subtile: QK^T (4 MFMA) -> softmax -> PV (4 MFMA)
static __device__ __forceinline__ void compute_subtile(
    const f16x8 (&K)[4], const f16x8 (&V)[4], uint32_t mw, int hi,
    const f16x8 (&qf)[4], const f32x16& fzero, uint32_t ones32,
    f32x16& acc0, f32x16& acc1, float& lsum)
{
    f32x16 sc;
    __builtin_amdgcn_s_setprio(1);
    sc = mfma32h(K[0], qf[0], fzero);
    sc = mfma32h(K[1], qf[1], sc);
    sc = mfma32h(K[2], qf[2], sc);
    sc = mfma32h(K[3], qf[3], sc);
    __builtin_amdgcn_s_setprio(0);

    uint32_t W8[8];
    softmax_pack(sc, mw >> (hi*4), W8, lsum, ones32);
    f16x8 pa0, pa1;
    assemble_pa(W8, pa0, pa1);

    __builtin_amdgcn_s_setprio(1);
    acc0 = mfma32h(pa0, V[0], acc0);
    acc1 = mfma32h(pa0, V[1], acc1);
    acc0 = mfma32h(pa1, V[2], acc0);
    acc1 = mfma32h(pa1, V[3], acc1);
    __builtin_amdgcn_s_setprio(0);
}

// ---- fused prep + pack: blocks [0,192) convert W -> bf16 hi/lo (+bias);
//      blocks [192, 192+2304) bitpack adjacency transposed ----
__global__ void preppack_kernel(const float* __restrict__ Wq, const float* __restrict__ Wk,
                                const float* __restrict__ Wv,
                                const float* __restrict__ bq, const float* __restrict__ bk,
                                const float* __restrict__ bv,
                                const int* __restrict__ edge,
                                __bf16* __restrict__ Wbh, __bf16* __restrict__ Wbl,
                                float* __restrict__ Bs, uint32_t* __restrict__ pmT)
{
    if (blockIdx.x < 192) {
        int i = blockIdx.x*256 + threadIdx.x;   // 49152
        int d = i & 63, o = (i >> 6) & 63, h = (i >> 12) & 3, p = i >> 14;
        const float* W = (p == 0) ? Wq : (p == 1) ? Wk : Wv;
        float scale = (p == 0) ? QSCALE : 1.0f;
        float val = W[(h*64 + d)*64 + o] * scale;
        int idx = (((p*Hc + h)*64 + o) << 6) + d;
        __bf16 hi = (__bf16)val;
        Wbh[idx] = hi;
        Wbl[idx] = (__bf16)(val - (float)hi);
        if (i < 3*Hc*64) {
            int pp = i / (Hc*64), rest = i % (Hc*64);
            const float* B = (pp == 0) ? bq : (pp == 1) ? bk : bv;
            Bs[i] = B[rest] * ((pp == 0) ? QSCALE : 1.0f);
        }
    } else {
        int gw = (blockIdx.x - 192)*4 + (threadIdx.x >> 6);
        int lane = threadIdx.x & 63;
        int ng = gw % 48; gw /= 48;
        int w  = gw % NW32; gw /= NW32;
        int b  = gw;
        int n = ng*64 + lane;
        const uint4* ep = (const uint4*)(edge + ((size_t)b*Nc + n)*Nc + w*32);
        uint32_t word = 0;
        #pragma unroll
        for (int i = 0; i < 8; ++i) {
            uint4 e = ep[i];
            word |= (e.x ? 1u : 0u) << (4*i);
            word |= (e.y ? 1u : 0u) << (4*i + 1);
            word |= (e.z ? 1u : 0u) << (4*i + 2);
            word |= (e.w ? 1u : 0u) << (4*i + 3);
        }
        pmT[((size_t)b*NW32 + w)*Nc + n] = word;
    }
}

// ---- QKV projection via MFMA (split-bf16, x converted in-register).
//      Q,K -> fp16 flat [bh][n][64]; V -> Vimg granules fp16 (4KB/32-key tile) ----
__global__ __launch_bounds__(256) void qkv_mfma(
    const float* __restrict__ x,
    const __bf16* __restrict__ Wbh, const __bf16* __restrict__ Wbl,
    const float* __restrict__ Bs,
    _Float16* __restrict__ Qf, _Float16* __restrict__ Kf,
    _Float16* __restrict__ Vimg)
{
    const int lane = threadIdx.x & 63, w = threadIdx.x >> 6;
    const int l31 = lane & 31, hi = lane >> 5;
    int t = blockIdx.x;                 // 1152 blocks
    int nt = t % 48; t /= 48;
    int b  = t & 1;  t >>= 1;
    int p  = t % 3;
    int h  = t / 3;
    const int r0 = (w >> 1)*32, c0 = (w & 1)*32, n0 = nt*64;

    bf16x8 xh[4], xl[4], wh[4], wl[4];
    #pragma unroll
    for (int kk = 0; kk < 4; ++kk) {
        size_t xoff = (((size_t)(b*Nc + n0 + r0 + l31)) << 6) + kk*16 + hi*8;
        float4 f0 = *(const float4*)(x + xoff);
        float4 f1 = *(const float4*)(x + xoff + 4);
        float xs[8] = {f0.x, f0.y, f0.z, f0.w, f1.x, f1.y, f1.z, f1.w};
        #pragma unroll
        for (int j = 0; j < 8; ++j) {
            __bf16 hh = (__bf16)xs[j];
            xh[kk][j] = hh;
            xl[kk][j] = (__bf16)(xs[j] - (float)hh);
        }
        size_t woff = (((size_t)((p*Hc + h)*64 + c0 + l31)) << 6) + kk*16 + hi*8;
        wh[kk] = *(const bf16x8*)(Wbh + woff);
        wl[kk] = *(const bf16x8*)(Wbl + woff);
    }
    float bias = Bs[(p*Hc + h)*64 + c0 + l31];
    f32x16 acc;
    #pragma unroll
    for (int i = 0; i < 16; ++i) acc[i] = bias;
    #pragma unroll
    for (int kk = 0; kk < 4; ++kk) {
        acc = mfma32bf(xh[kk], wh[kk], acc);
        acc = mfma32bf(xl[kk], wh[kk], acc);
        acc = mfma32bf(xh[kk], wl[kk], acc);
    }
    const int bh = b*Hc + h;
    if (p < 2) {
        _Float16* dst = (p == 0) ? Qf : Kf;
        #pragma unroll
        for (int r = 0; r < 16; ++r) {
            int row = (r & 3) + 8*(r >> 2) + 4*hi;
            size_t idx = (((size_t)bh*Nc + n0 + r0 + row) << 6) + c0 + l31;
            dst[idx] = (_Float16)acc[r];
        }
    } else {
        // V image granule (kb,o) = V[kb*8..+7][o], fp16, tile = 4KB
        const int t_img = (n0 + r0) >> 5;
        char* img = (char*)Vimg + (((size_t)(bh*96 + t_img)) << 12);
        #pragma unroll
        for (int grp = 0; grp < 2; ++grp) {
            uint32_t wH[4];
            #pragma unroll
            for (int j = 0; j < 4; ++j)
                wH[j] = pkrtz(acc[grp*8 + 2*j], acc[grp*8 + 2*j + 1]);
            asm("v_permlane32_swap_b32 %0, %1" : "+v"(wH[0]), "+v"(wH[2]));
            asm("v_permlane32_swap_b32 %0, %1" : "+v"(wH[1]), "+v"(wH[3]));
            const int kb = grp*2 + hi;
            const int o  = c0 + l31;
            uint4 gh = {wH[0], wH[1], wH[2], wH[3]};
            *(uint4*)(img + ((kb*64 + o) << 4)) = gh;
        }
    }
}

// ---- flash attention fp16: 4 independent waves/block, 6 blocks/CU (KSC=8),
//      K from flat Kf, V from Vimg, all register-direct (no LDS, no barriers) ----
__global__ __launch_bounds__(256, 4) void attn_mfma(
    const _Float16* __restrict__ Qf, const _Float16* __restrict__ Kf,
    const _Float16* __restrict__ Vimg, const uint32_t* __restrict__ pmT,
    float* __restrict__ PA, float* __restrict__ PL)
{
    const int lane = threadIdx.x & 63, w = threadIdx.x >> 6;  // w in [0,4)
    const int l31 = lane & 31, hi = lane >> 5;
    int gb = blockIdx.x;
    const int bh = gb & 7; gb >>= 3;        // XCD swizzle: one bh per XCD
    const int qt = gb % 24;
    const int ks = gb / 24;
    const int b = bh >> 2;
    const int qrow0 = qt*128 + w*32;
    const int t0 = ks*TPS;                  // in 32-key subtiles

    const uint32_t* pmp = pmT + ((size_t)b*NW32 + t0)*Nc + qrow0 + l31;
    // K: lane reads Kf[key = t*32 + l31][(kk*2+hi)*8 ..+8]
    const char* gk = (const char*)Kf + (((size_t)(bh*Nc + t0*32 + l31)) << 7);
    const char* gv = (const char*)Vimg + (((size_t)(bh*96 + t0)) << 12);

    // Q B-frags (col = q-row = l31, k = d), pre-scaled by QSCALE, fp16
    f16x8 qf[4];
    #pragma unroll
    for (int kk = 0; kk < 4; ++kk) {
        size_t qoff = (((size_t)bh*Nc + qrow0 + l31) << 6) + kk*16 + hi*8;
        qf[kk] = *(const f16x8*)(Qf + qoff);
    }
    f32x16 fzero;
    #pragma unroll
    for (int i = 0; i < 16; ++i) fzero[i] = 0.f;
    const uint32_t ones32 = 0x3C003C00u;    // packed fp16 {1.0, 1.0}

    f32x16 acc0 = fzero, acc1 = fzero;
    float lsum = 0.f;

    // A/B register sets, prefetch-1 pipeline
    f16x8 KA[4], VA[4], KB[4], VB[4];
    uint32_t mwA, mwB;
    load_subtile(gk, gv, hi, l31, KA, VA);
    mwA = pmp[0];

    #pragma unroll 1
    for (int j = 0; j < TPS/2; ++j) {       // 6 pair-iterations
        load_subtile(gk + (size_t)(2*j + 1)*4096, gv + (size_t)(2*j + 1)*4096,
                     hi, l31, KB, VB);
        mwB = pmp[(size_t)(2*j + 1)*Nc];
        compute_subtile(KA, VA, mwA, hi, qf, fzero, ones32, acc0, acc1, lsum);
        const int tn = (2*j + 2 < TPS) ? (2*j + 2) : 0;   // tail clamp (unused)
        load_subtile(gk + (size_t)tn*4096, gv + (size_t)tn*4096, hi, l31, KA, VA);
        mwA = pmp[(size_t)tn*Nc];
        compute_subtile(KB, VB, mwB, hi, qf, fzero, ones32, acc0, acc1, lsum);
    }

    // ---- epilogue: PA[bh][ks][n][o], PL[bh][ks][n] ----
    lsum += __shfl_xor(lsum, 32);           // combine hi halves (16+16 keys)
    float* po = PA + (((size_t)(bh*KSC + ks)*Nc + qrow0) << 6);
    #pragma unroll
    for (int r = 0; r < 16; ++r) {
        int row = (r & 3) + 8*(r >> 2) + 4*hi;
        po[((size_t)row << 6) + l31]      = acc0[r];
        po[((size_t)row << 6) + 32 + l31] = acc1[r];
    }
    if (lane < 32)
        PL[(size_t)(bh*KSC + ks)*Nc + qrow0 + l31] = lsum;
}

// ---- merge: sum key-splits, divide, mean heads, leaky ----
__global__ void merge_kernel(const float* __restrict__ PA, const float* __restrict__ PL,
                             float* __restrict__ out)
{
    int gid = blockIdx.x*256 + threadIdx.x;
    int o  = gid & 63;
    int bn = gid >> 6;
    int n  = bn % Nc;
    int b  = bn / Nc;
    float ft = 0.f;
    for (int h = 0; h < Hc; ++h) {
        int bh = b*Hc + h;
        float A = 0.f, L = 0.f;
        for (int ks = 0; ks < KSC; ++ks) {
            A += PA[(((size_t)(bh*KSC + ks)*Nc + n) << 6) + o];
            L += PL[(size_t)(bh*KSC + ks)*Nc + n];
        }
        ft += A / L;
    }
    ft *= 0.25f;
    out[((size_t)bn << 6) + o] = fmaxf(ft, 0.f) + 0.2f*fminf(ft, 0.f);
}

extern "C" void kernel_launch(void* const* d_in, const int* in_sizes, int n_in,
                              void* d_out, int out_size, void* d_ws, size_t ws_size,
                              hipStream_t stream)
{
    const float* x    = (const float*)d_in[0];
    const int*   edge = (const int*)d_in[1];
    const float* Wv   = (const float*)d_in[2];
    const float* bv   = (const float*)d_in[3];
    const float* Wq   = (const float*)d_in[4];
    const float* bq   = (const float*)d_in[5];
    const float* Wk   = (const float*)d_in[6];
    const float* bk   = (const float*)d_in[7];
    float* out = (float*)d_out;

    const size_t PROJ = (size_t)Bc*Hc*Nc*64;
    char* p = (char*)d_ws;
    __bf16* Wbh = (__bf16*)p;     p += 49152*2;
    __bf16* Wbl = (__bf16*)p;     p += 49152*2;
    float*  Bs  = (float*)p;      p += 4096;
    _Float16* Qf = (_Float16*)p;  p += PROJ*2;
    _Float16* Kf = (_Float16*)p;  p += PROJ*2;
    _Float16* Vimg = (_Float16*)p; p += ((size_t)Bc*Hc*96) << 12;
    uint32_t* pmT = (uint32_t*)p; p += (size_t)Bc*NW32*Nc*4;
    float* PA = (float*)p;        p += (size_t)Bc*Hc*KSC*Nc*64*4;
    float* PL = (float*)p;

    hipLaunchKernelGGL(preppack_kernel, dim3(192 + Bc*NW32*48/4), dim3(256), 0, stream,
                       Wq, Wk, Wv, bq, bk, bv, edge, Wbh, Wbl, Bs, pmT);
    hipLaunchKernelGGL(qkv_mfma,    dim3(1152), dim3(256), 0, stream,
                       x, Wbh, Wbl, Bs, Qf, Kf, Vimg);
    hipLaunchKernelGGL(attn_mfma,   dim3(8*KSC*24), dim3(256), 0, stream,
                       Qf, Kf, Vimg, pmT, PA, PL);
    hipLaunchKernelGGL(merge_kernel, dim3((Bc*Nc*64)/256), dim3(256), 0, stream,
                       PA, PL, out);
}

// Round 16
// 93.557 us; speedup vs baseline: 1.3925x; 1.3925x over previous
//
#include <hip/hip_runtime.h>
#include <hip/hip_bf16.h>
#include <cstdint>

#define Bc 2
#define Nc 3072
#define Hc 4
#define NW32 96      // 32-key subtiles per row
#define KSC 8        // key splits
#define TPS (NW32/KSC)   // 12 subtiles per split

typedef __bf16    bf16x8 __attribute__((ext_vector_type(8)));
typedef _Float16  f16x8  __attribute__((ext_vector_type(8)));
typedef float     f32x16 __attribute__((ext_vector_type(16)));

#define QSCALE 0.18033688f   // 0.125 * log2(e): exp(s/8) == exp2(s*QSCALE)

static __device__ __forceinline__ f32x16 mfma32bf(bf16x8 a, bf16x8 b, f32x16 c) {
    return __builtin_amdgcn_mfma_f32_32x32x16_bf16(a, b, c, 0, 0, 0);
}
static __device__ __forceinline__ f32x16 mfma32h(f16x8 a, f16x8 b, f32x16 c) {
    return __builtin_amdgcn_mfma_f32_32x32x16_f16(a, b, c, 0, 0, 0);
}
static __device__ __forceinline__ uint32_t pkrtz(float lo, float hi) {
    uint32_t w;
    asm("v_cvt_pkrtz_f16_f32 %0, %1, %2" : "=v"(w) : "v"(lo), "v"(hi));
    return w;
}

// softmax for one 32-key subtile (16 scores/lane): leaky+exp2, pack to fp16,
// mask the PACKED word, denominator via v_dot2 on the same masked packed values
static __device__ __forceinline__ void softmax_pack(const f32x16& sc, uint32_t mwh,
                                                    uint32_t W8[8], float& lsum,
                                                    uint32_t ones32)
{
    #pragma unroll
    for (int i = 0; i < 8; ++i) {
        const int bp0 = (2*i & 3) + 8*(2*i >> 2);   // bp1 = bp0+1
        float s0 = sc[2*i], s1 = sc[2*i + 1];
        float a0 = fmaxf(s0, 0.2f*s0);
        float a1 = fmaxf(s1, 0.2f*s1);
        float e0, e1;
        asm("v_exp_f32 %0, %1" : "=v"(e0) : "v"(a0));   // exp2 (log2e pre-folded)
        asm("v_exp_f32 %0, %1" : "=v"(e1) : "v"(a1));
        uint32_t pk = pkrtz(e0, e1);
        uint32_t m0 = (uint32_t)(((int)(mwh << (31 - bp0))) >> 31);
        uint32_t m1 = (uint32_t)(((int)(mwh << (30 - bp0))) >> 31);
        uint32_t wv = pk & ((m0 & 0x0000ffffu) | (m1 & 0xffff0000u));
        W8[i] = wv;
        asm("v_dot2_f32_f16 %0, %1, %2, %0" : "+v"(lsum) : "v"(wv), "v"(ones32));
    }
}

static __device__ __forceinline__ void assemble_pa(uint32_t W8[8], f16x8& pa0, f16x8& pa1)
{
    uint32_t a0 = W8[0], a2 = W8[2], a1 = W8[1], a3 = W8[3];
    uint32_t b0 = W8[4], b2 = W8[6], b1 = W8[5], b3 = W8[7];
    asm("v_permlane32_swap_b32 %0, %1" : "+v"(a0), "+v"(a2));
    asm("v_permlane32_swap_b32 %0, %1" : "+v"(a1), "+v"(a3));
    asm("v_permlane32_swap_b32 %0, %1" : "+v"(b0), "+v"(b2));
    asm("v_permlane32_swap_b32 %0, %1" : "+v"(b1), "+v"(b3));
    union { uint32_t u[4]; f16x8 v; } u0, u1;
    u0.u[0] = a0; u0.u[1] = a1; u0.u[2] = a2; u0.u[3] = a3;
    u1.u[0] = b0; u1.u[1] = b1; u1.u[2] = b2; u1.u[3] = b3;
    pa0 = u0.v; pa1 = u1.v;
}

// load one subtile's K (flat Kf) and V (Vimg granules) fragments into registers
static __device__ __forceinline__ void load_subtile(const char* gk, const char* gv,
                                                    int hi, int l31,
                                                    f16x8 (&K)[4], f16x8 (&V)[4])
{
    #pragma unroll
    for (int kk = 0; kk < 4; ++kk)
        K[kk] = *(const f16x8*)(gk + ((kk*2 + hi) << 4));
    #pragma unroll
    for (int i = 0; i < 4; ++i) {
        const int kkp = i >> 1, ot = i & 1;
        V[i] = *(const f16x8*)(gv + ((kkp*2 + hi) << 10) + ((ot*32 + l31) << 4));
    }
}

// full compute for one subtile: QK^T (4 MFMA) -> softmax -> PV (4 MFMA)
static __device__ __forceinline__ void compute_subtile(
    const f16x8 (&K)[4], const f16x8 (&V)[4], uint32_t mw, int hi,
    const f16x8 (&qf)[4], const f32x16& fzero, uint32_t ones32,
    f32x16& acc0, f32x16& acc1, float& lsum)
{
    f32x16 sc;
    __builtin_amdgcn_s_setprio(1);
    sc = mfma32h(K[0], qf[0], fzero);
    sc = mfma32h(K[1], qf[1], sc);
    sc = mfma32h(K[2], qf[2], sc);
    sc = mfma32h(K[3], qf[3], sc);
    __builtin_amdgcn_s_setprio(0);

    uint32_t W8[8];
    softmax_pack(sc, mw >> (hi*4), W8, lsum, ones32);
    f16x8 pa0, pa1;
    assemble_pa(W8, pa0, pa1);

    __builtin_amdgcn_s_setprio(1);
    acc0 = mfma32h(pa0, V[0], acc0);
    acc1 = mfma32h(pa0, V[1], acc1);
    acc0 = mfma32h(pa1, V[2], acc0);
    acc1 = mfma32h(pa1, V[3], acc1);
    __builtin_amdgcn_s_setprio(0);
}

// ---- fused prep + pack: blocks [0,192) convert W -> bf16 hi/lo (+bias);
//      blocks [192, 192+2304) bitpack adjacency transposed ----
__global__ void preppack_kernel(const float* __restrict__ Wq, const float* __restrict__ Wk,
                                const float* __restrict__ Wv,
                                const float* __restrict__ bq, const float* __restrict__ bk,
                                const float* __restrict__ bv,
                                const int* __restrict__ edge,
                                __bf16* __restrict__ Wbh, __bf16* __restrict__ Wbl,
                                float* __restrict__ Bs, uint32_t* __restrict__ pmT)
{
    if (blockIdx.x < 192) {
        int i = blockIdx.x*256 + threadIdx.x;   // 49152
        int d = i & 63, o = (i >> 6) & 63, h = (i >> 12) & 3, p = i >> 14;
        const float* W = (p == 0) ? Wq : (p == 1) ? Wk : Wv;
        float scale = (p == 0) ? QSCALE : 1.0f;
        float val = W[(h*64 + d)*64 + o] * scale;
        int idx = (((p*Hc + h)*64 + o) << 6) + d;
        __bf16 hi = (__bf16)val;
        Wbh[idx] = hi;
        Wbl[idx] = (__bf16)(val - (float)hi);
        if (i < 3*Hc*64) {
            int pp = i / (Hc*64), rest = i % (Hc*64);
            const float* B = (pp == 0) ? bq : (pp == 1) ? bk : bv;
            Bs[i] = B[rest] * ((pp == 0) ? QSCALE : 1.0f);
        }
    } else {
        int gw = (blockIdx.x - 192)*4 + (threadIdx.x >> 6);
        int lane = threadIdx.x & 63;
        int ng = gw % 48; gw /= 48;
        int w  = gw % NW32; gw /= NW32;
        int b  = gw;
        int n = ng*64 + lane;
        const uint4* ep = (const uint4*)(edge + ((size_t)b*Nc + n)*Nc + w*32);
        uint32_t word = 0;
        #pragma unroll
        for (int i = 0; i < 8; ++i) {
            uint4 e = ep[i];
            word |= (e.x ? 1u : 0u) << (4*i);
            word |= (e.y ? 1u : 0u) << (4*i + 1);
            word |= (e.z ? 1u : 0u) << (4*i + 2);
            word |= (e.w ? 1u : 0u) << (4*i + 3);
        }
        pmT[((size_t)b*NW32 + w)*Nc + n] = word;
    }
}

// ---- QKV projection via MFMA (split-bf16, x converted in-register).
//      Q,K -> fp16 flat [bh][n][64]; V -> Vimg granules fp16 (4KB/32-key tile) ----
__global__ __launch_bounds__(256) void qkv_mfma(
    const float* __restrict__ x,
    const __bf16* __restrict__ Wbh, const __bf16* __restrict__ Wbl,
    const float* __restrict__ Bs,
    _Float16* __restrict__ Qf, _Float16* __restrict__ Kf,
    _Float16* __restrict__ Vimg)
{
    const int lane = threadIdx.x & 63, w = threadIdx.x >> 6;
    const int l31 = lane & 31, hi = lane >> 5;
    int t = blockIdx.x;                 // 1152 blocks
    int nt = t % 48; t /= 48;
    int b  = t & 1;  t >>= 1;
    int p  = t % 3;
    int h  = t / 3;
    const int r0 = (w >> 1)*32, c0 = (w & 1)*32, n0 = nt*64;

    bf16x8 xh[4], xl[4], wh[4], wl[4];
    #pragma unroll
    for (int kk = 0; kk < 4; ++kk) {
        size_t xoff = (((size_t)(b*Nc + n0 + r0 + l31)) << 6) + kk*16 + hi*8;
        float4 f0 = *(const float4*)(x + xoff);
        float4 f1 = *(const float4*)(x + xoff + 4);
        float xs[8] = {f0.x, f0.y, f0.z, f0.w, f1.x, f1.y, f1.z, f1.w};
        #pragma unroll
        for (int j = 0; j < 8; ++j) {
            __bf16 hh = (__bf16)xs[j];
            xh[kk][j] = hh;
            xl[kk][j] = (__bf16)(xs[j] - (float)hh);
        }
        size_t woff = (((size_t)((p*Hc + h)*64 + c0 + l31)) << 6) + kk*16 + hi*8;
        wh[kk] = *(const bf16x8*)(Wbh + woff);
        wl[kk] = *(const bf16x8*)(Wbl + woff);
    }
    float bias = Bs[(p*Hc + h)*64 + c0 + l31];
    f32x16 acc;
    #pragma unroll
    for (int i = 0; i < 16; ++i) acc[i] = bias;
    #pragma unroll
    for (int kk = 0; kk < 4; ++kk) {
        acc = mfma32bf(xh[kk], wh[kk], acc);
        acc = mfma32bf(xl[kk], wh[kk], acc);
        acc = mfma32bf(xh[kk], wl[kk], acc);
    }
    const int bh = b*Hc + h;
    if (p < 2) {
        _Float16* dst = (p == 0) ? Qf : Kf;
        #pragma unroll
        for (int r = 0; r < 16; ++r) {
            int row = (r & 3) + 8*(r >> 2) + 4*hi;
            size_t idx = (((size_t)bh*Nc + n0 + r0 + row) << 6) + c0 + l31;
            dst[idx] = (_Float16)acc[r];
        }
    } else {
        // V image granule (kb,o) = V[kb*8..+7][o], fp16, tile = 4KB
        const int t_img = (n0 + r0) >> 5;
        char* img = (char*)Vimg + (((size_t)(bh*96 + t_img)) << 12);
        #pragma unroll
        for (int grp = 0; grp < 2; ++grp) {
            uint32_t wH[4];
            #pragma unroll
            for (int j = 0; j < 4; ++j)
                wH[j] = pkrtz(acc[grp*8 + 2*j], acc[grp*8 + 2*j + 1]);
            asm("v_permlane32_swap_b32 %0, %1" : "+v"(wH[0]), "+v"(wH[2]));
            asm("v_permlane32_swap_b32 %0, %1" : "+v"(wH[1]), "+v"(wH[3]));
            const int kb = grp*2 + hi;
            const int o  = c0 + l31;
            uint4 gh = {wH[0], wH[1], wH[2], wH[3]};
            *(uint4*)(img + ((kb*64 + o) << 4)) = gh;
        }
    }
}

// ---- flash attention fp16: 4 independent waves/block, KSC=8 -> 1536 blocks
//      (6 blocks/CU), K from flat Kf, V from Vimg, register-direct, no LDS,
//      no barriers. launch_bounds min-waves=3 so VGPR cap stays 170 (no spill);
//      actual occupancy limited by VGPR (~80-100 -> 5-6 waves/SIMD). ----
__global__ __launch_bounds__(256, 3) void attn_mfma(
    const _Float16* __restrict__ Qf, const _Float16* __restrict__ Kf,
    const _Float16* __restrict__ Vimg, const uint32_t* __restrict__ pmT,
    float* __restrict__ PA, float* __restrict__ PL)
{
    const int lane = threadIdx.x & 63, w = threadIdx.x >> 6;  // w in [0,4)
    const int l31 = lane & 31, hi = lane >> 5;
    int gb = blockIdx.x;
    const int bh = gb & 7; gb >>= 3;        // XCD swizzle: one bh per XCD
    const int qt = gb % 24;
    const int ks = gb / 24;
    const int b = bh >> 2;
    const int qrow0 = qt*128 + w*32;
    const int t0 = ks*TPS;                  // in 32-key subtiles

    const uint32_t* pmp = pmT + ((size_t)b*NW32 + t0)*Nc + qrow0 + l31;
    // K: lane reads Kf[key = t*32 + l31][(kk*2+hi)*8 ..+8]
    const char* gk = (const char*)Kf + (((size_t)(bh*Nc + t0*32 + l31)) << 7);
    const char* gv = (const char*)Vimg + (((size_t)(bh*96 + t0)) << 12);

    // Q B-frags (col = q-row = l31, k = d), pre-scaled by QSCALE, fp16
    f16x8 qf[4];
    #pragma unroll
    for (int kk = 0; kk < 4; ++kk) {
        size_t qoff = (((size_t)bh*Nc + qrow0 + l31) << 6) + kk*16 + hi*8;
        qf[kk] = *(const f16x8*)(Qf + qoff);
    }
    f32x16 fzero;
    #pragma unroll
    for (int i = 0; i < 16; ++i) fzero[i] = 0.f;
    const uint32_t ones32 = 0x3C003C00u;    // packed fp16 {1.0, 1.0}

    f32x16 acc0 = fzero, acc1 = fzero;
    float lsum = 0.f;

    // A/B register sets, prefetch-1 pipeline
    f16x8 KA[4], VA[4], KB[4], VB[4];
    uint32_t mwA, mwB;
    load_subtile(gk, gv, hi, l31, KA, VA);
    mwA = pmp[0];

    #pragma unroll 1
    for (int j = 0; j < TPS/2; ++j) {       // 6 pair-iterations
        load_subtile(gk + (size_t)(2*j + 1)*4096, gv + (size_t)(2*j + 1)*4096,
                     hi, l31, KB, VB);
        mwB = pmp[(size_t)(2*j + 1)*Nc];
        compute_subtile(KA, VA, mwA, hi, qf, fzero, ones32, acc0, acc1, lsum);
        const int tn = (2*j + 2 < TPS) ? (2*j + 2) : 0;   // tail clamp (unused)
        load_subtile(gk + (size_t)tn*4096, gv + (size_t)tn*4096, hi, l31, KA, VA);
        mwA = pmp[(size_t)tn*Nc];
        compute_subtile(KB, VB, mwB, hi, qf, fzero, ones32, acc0, acc1, lsum);
    }

    // ---- epilogue: PA[bh][ks][n][o], PL[bh][ks][n] ----
    lsum += __shfl_xor(lsum, 32);           // combine hi halves (16+16 keys)
    float* po = PA + (((size_t)(bh*KSC + ks)*Nc + qrow0) << 6);
    #pragma unroll
    for (int r = 0; r < 16; ++r) {
        int row = (r & 3) + 8*(r >> 2) + 4*hi;
        po[((size_t)row << 6) + l31]      = acc0[r];
        po[((size_t)row << 6) + 32 + l31] = acc1[r];
    }
    if (lane < 32)
        PL[(size_t)(bh*KSC + ks)*Nc + qrow0 + l31] = lsum;
}

// ---- merge: sum key-splits, divide, mean heads, leaky ----
__global__ void merge_kernel(const float* __restrict__ PA, const float* __restrict__ PL,
                             float* __restrict__ out)
{
    int gid = blockIdx.x*256 + threadIdx.x;
    int o  = gid & 63;
    int bn = gid >> 6;
    int n  = bn % Nc;
    int b  = bn / Nc;
    float ft = 0.f;
    for (int h = 0; h < Hc; ++h) {
        int bh = b*Hc + h;
        float A = 0.f, L = 0.f;
        for (int ks = 0; ks < KSC; ++ks) {
            A += PA[(((size_t)(bh*KSC + ks)*Nc + n) << 6) + o];
            L += PL[(size_t)(bh*KSC + ks)*Nc + n];
        }
        ft += A / L;
    }
    ft *= 0.25f;
    out[((size_t)bn << 6) + o] = fmaxf(ft, 0.f) + 0.2f*fminf(ft, 0.f);
}

extern "C" void kernel_launch(void* const* d_in, const int* in_sizes, int n_in,
                              void* d_out, int out_size, void* d_ws, size_t ws_size,
                              hipStream_t stream)
{
    const float* x    = (const float*)d_in[0];
    const int*   edge = (const int*)d_in[1];
    const float* Wv   = (const float*)d_in[2];
    const float* bv   = (const float*)d_in[3];
    const float* Wq   = (const float*)d_in[4];
    const float* bq   = (const float*)d_in[5];
    const float* Wk   = (const float*)d_in[6];
    const float* bk   = (const float*)d_in[7];
    float* out = (float*)d_out;

    const size_t PROJ = (size_t)Bc*Hc*Nc*64;
    char* p = (char*)d_ws;
    __bf16* Wbh = (__bf16*)p;     p += 49152*2;
    __bf16* Wbl = (__bf16*)p;     p += 49152*2;
    float*  Bs  = (float*)p;      p += 4096;
    _Float16* Qf = (_Float16*)p;  p += PROJ*2;
    _Float16* Kf = (_Float16*)p;  p += PROJ*2;
    _Float16* Vimg = (_Float16*)p; p += ((size_t)Bc*Hc*96) << 12;
    uint32_t* pmT = (uint32_t*)p; p += (size_t)Bc*NW32*Nc*4;
    float* PA = (float*)p;        p += (size_t)Bc*Hc*KSC*Nc*64*4;
    float* PL = (float*)p;

    hipLaunchKernelGGL(preppack_kernel, dim3(192 + Bc*NW32*48/4), dim3(256), 0, stream,
                       Wq, Wk, Wv, bq, bk, bv, edge, Wbh, Wbl, Bs, pmT);
    hipLaunchKernelGGL(qkv_mfma,    dim3(1152), dim3(256), 0, stream,
                       x, Wbh, Wbl, Bs, Qf, Kf, Vimg);
    hipLaunchKernelGGL(attn_mfma,   dim3(8*KSC*24), dim3(256), 0, stream,
                       Qf, Kf, Vimg, pmT, PA, PL);
    hipLaunchKernelGGL(merge_kernel, dim3((Bc*Nc*64)/256), dim3(256), 0, stream,
                       PA, PL, out);
}

// Round 17
// 78.859 us; speedup vs baseline: 1.6521x; 1.1864x over previous
//
#include <hip/hip_runtime.h>
#include <hip/hip_bf16.h>
#include <cstdint>

#define Bc 2
#define Nc 3072
#define Hc 4
#define NW32 96      // 32-key subtiles per row
#define TILEB 8192   // per 32-key fp16 image tile: K 4KB | V 4KB
#define KSC 8        // key splits -> grid 1536 = 6 blocks/CU
#define TPS (NW32/KSC)   // 12 subtiles per split

typedef __bf16    bf16x8 __attribute__((ext_vector_type(8)));
typedef _Float16  f16x8  __attribute__((ext_vector_type(8)));
typedef float     f32x16 __attribute__((ext_vector_type(16)));

#define QSCALE 0.18033688f   // 0.125 * log2(e): exp(s/8) == exp2(s*QSCALE)

static __device__ __forceinline__ f32x16 mfma32bf(bf16x8 a, bf16x8 b, f32x16 c) {
    return __builtin_amdgcn_mfma_f32_32x32x16_bf16(a, b, c, 0, 0, 0);
}
static __device__ __forceinline__ f32x16 mfma32h(f16x8 a, f16x8 b, f32x16 c) {
    return __builtin_amdgcn_mfma_f32_32x32x16_f16(a, b, c, 0, 0, 0);
}
static __device__ __forceinline__ uint32_t pkrtz(float lo, float hi) {
    uint32_t w;
    asm("v_cvt_pkrtz_f16_f32 %0, %1, %2" : "=v"(w) : "v"(lo), "v"(hi));
    return w;
}

// softmax for one 32-key subtile (16 scores/lane): leaky+exp2, pack to fp16,
// mask the PACKED word, denominator via v_dot2 on the same masked packed values
static __device__ __forceinline__ void softmax_pack(const f32x16& sc, uint32_t mwh,
                                                    uint32_t W8[8], float& lsum,
                                                    uint32_t ones32)
{
    #pragma unroll
    for (int i = 0; i < 8; ++i) {
        const int bp0 = (2*i & 3) + 8*(2*i >> 2);   // bp1 = bp0+1
        float s0 = sc[2*i], s1 = sc[2*i + 1];
        float a0 = fmaxf(s0, 0.2f*s0);
        float a1 = fmaxf(s1, 0.2f*s1);
        float e0, e1;
        asm("v_exp_f32 %0, %1" : "=v"(e0) : "v"(a0));   // exp2 (log2e pre-folded)
        asm("v_exp_f32 %0, %1" : "=v"(e1) : "v"(a1));
        uint32_t pk = pkrtz(e0, e1);
        uint32_t m0 = (uint32_t)(((int)(mwh << (31 - bp0))) >> 31);
        uint32_t m1 = (uint32_t)(((int)(mwh << (30 - bp0))) >> 31);
        uint32_t wv = pk & ((m0 & 0x0000ffffu) | (m1 & 0xffff0000u));
        W8[i] = wv;
        asm("v_dot2_f32_f16 %0, %1, %2, %0" : "+v"(lsum) : "v"(wv), "v"(ones32));
    }
}

static __device__ __forceinline__ void assemble_pa(uint32_t W8[8], f16x8& pa0, f16x8& pa1)
{
    uint32_t a0 = W8[0], a2 = W8[2], a1 = W8[1], a3 = W8[3];
    uint32_t b0 = W8[4], b2 = W8[6], b1 = W8[5], b3 = W8[7];
    asm("v_permlane32_swap_b32 %0, %1" : "+v"(a0), "+v"(a2));
    asm("v_permlane32_swap_b32 %0, %1" : "+v"(a1), "+v"(a3));
    asm("v_permlane32_swap_b32 %0, %1" : "+v"(b0), "+v"(b2));
    asm("v_permlane32_swap_b32 %0, %1" : "+v"(b1), "+v"(b3));
    union { uint32_t u[4]; f16x8 v; } u0, u1;
    u0.u[0] = a0; u0.u[1] = a1; u0.u[2] = a2; u0.u[3] = a3;
    u1.u[0] = b0; u1.u[1] = b1; u1.u[2] = b2; u1.u[3] = b3;
    pa0 = u0.v; pa1 = u1.v;
}

// load one subtile's K/V fragments from KVimg (granule layout, contiguous) to regs
static __device__ __forceinline__ void load_subtile(const char* gt, int hi, int l31,
                                                    f16x8 (&K)[4], f16x8 (&V)[4])
{
    #pragma unroll
    for (int kk = 0; kk < 4; ++kk)
        K[kk] = *(const f16x8*)(gt + ((kk*2 + hi) << 9) + (l31 << 4));
    #pragma unroll
    for (int i = 0; i < 4; ++i) {
        const int kkp = i >> 1, ot = i & 1;
        V[i] = *(const f16x8*)(gt + 4096 + ((kkp*2 + hi) << 10) + ((ot*32 + l31) << 4));
    }
}

// full compute for one subtile: QK^T (4 MFMA) -> softmax -> PV (4 MFMA)
static __device__ __forceinline__ void compute_subtile(
    const f16x8 (&K)[4], const f16x8 (&V)[4], uint32_t mw, int hi,
    const f16x8 (&qf)[4], const f32x16& fzero, uint32_t ones32,
    f32x16& acc0, f32x16& acc1, float& lsum)
{
    f32x16 sc;
    __builtin_amdgcn_s_setprio(1);
    sc = mfma32h(K[0], qf[0], fzero);
    sc = mfma32h(K[1], qf[1], sc);
    sc = mfma32h(K[2], qf[2], sc);
    sc = mfma32h(K[3], qf[3], sc);
    __builtin_amdgcn_s_setprio(0);

    uint32_t W8[8];
    softmax_pack(sc, mw >> (hi*4), W8, lsum, ones32);
    f16x8 pa0, pa1;
    assemble_pa(W8, pa0, pa1);

    __builtin_amdgcn_s_setprio(1);
    acc0 = mfma32h(pa0, V[0], acc0);
    acc1 = mfma32h(pa0, V[1], acc1);
    acc0 = mfma32h(pa1, V[2], acc0);
    acc1 = mfma32h(pa1, V[3], acc1);
    __builtin_amdgcn_s_setprio(0);
}

// ---- fused prep + pack: blocks [0,192) convert W -> bf16 hi/lo (+bias);
//      blocks [192, 192+2304) bitpack adjacency transposed ----
__global__ void preppack_kernel(const float* __restrict__ Wq, const float* __restrict__ Wk,
                                const float* __restrict__ Wv,
                                const float* __restrict__ bq, const float* __restrict__ bk,
                                const float* __restrict__ bv,
                                const int* __restrict__ edge,
                                __bf16* __restrict__ Wbh, __bf16* __restrict__ Wbl,
                                float* __restrict__ Bs, uint32_t* __restrict__ pmT)
{
    if (blockIdx.x < 192) {
        int i = blockIdx.x*256 + threadIdx.x;   // 49152
        int d = i & 63, o = (i >> 6) & 63, h = (i >> 12) & 3, p = i >> 14;
        const float* W = (p == 0) ? Wq : (p == 1) ? Wk : Wv;
        float scale = (p == 0) ? QSCALE : 1.0f;
        float val = W[(h*64 + d)*64 + o] * scale;
        int idx = (((p*Hc + h)*64 + o) << 6) + d;
        __bf16 hi = (__bf16)val;
        Wbh[idx] = hi;
        Wbl[idx] = (__bf16)(val - (float)hi);
        if (i < 3*Hc*64) {
            int pp = i / (Hc*64), rest = i % (Hc*64);
            const float* B = (pp == 0) ? bq : (pp == 1) ? bk : bv;
            Bs[i] = B[rest] * ((pp == 0) ? QSCALE : 1.0f);
        }
    } else {
        int gw = (blockIdx.x - 192)*4 + (threadIdx.x >> 6);
        int lane = threadIdx.x & 63;
        int ng = gw % 48; gw /= 48;
        int w  = gw % NW32; gw /= NW32;
        int b  = gw;
        int n = ng*64 + lane;
        const uint4* ep = (const uint4*)(edge + ((size_t)b*Nc + n)*Nc + w*32);
        uint32_t word = 0;
        #pragma unroll
        for (int i = 0; i < 8; ++i) {
            uint4 e = ep[i];
            word |= (e.x ? 1u : 0u) << (4*i);
            word |= (e.y ? 1u : 0u) << (4*i + 1);
            word |= (e.z ? 1u : 0u) << (4*i + 2);
            word |= (e.w ? 1u : 0u) << (4*i + 3);
        }
        pmT[((size_t)b*NW32 + w)*Nc + n] = word;
    }
}

// ---- QKV projection via MFMA (split-bf16, x converted in-register).
//      Q,K -> fp16 flat [bh][n][64]; V -> KVimg granules (tile offset 4096) ----
__global__ __launch_bounds__(256) void qkv_mfma(
    const float* __restrict__ x,
    const __bf16* __restrict__ Wbh, const __bf16* __restrict__ Wbl,
    const float* __restrict__ Bs,
    _Float16* __restrict__ Qf, _Float16* __restrict__ Kf,
    _Float16* __restrict__ KVimg)
{
    const int lane = threadIdx.x & 63, w = threadIdx.x >> 6;
    const int l31 = lane & 31, hi = lane >> 5;
    int t = blockIdx.x;                 // 1152 blocks
    int nt = t % 48; t /= 48;
    int b  = t & 1;  t >>= 1;
    int p  = t % 3;
    int h  = t / 3;
    const int r0 = (w >> 1)*32, c0 = (w & 1)*32, n0 = nt*64;

    bf16x8 xh[4], xl[4], wh[4], wl[4];
    #pragma unroll
    for (int kk = 0; kk < 4; ++kk) {
        size_t xoff = (((size_t)(b*Nc + n0 + r0 + l31)) << 6) + kk*16 + hi*8;
        float4 f0 = *(const float4*)(x + xoff);
        float4 f1 = *(const float4*)(x + xoff + 4);
        float xs[8] = {f0.x, f0.y, f0.z, f0.w, f1.x, f1.y, f1.z, f1.w};
        #pragma unroll
        for (int j = 0; j < 8; ++j) {
            __bf16 hh = (__bf16)xs[j];
            xh[kk][j] = hh;
            xl[kk][j] = (__bf16)(xs[j] - (float)hh);
        }
        size_t woff = (((size_t)((p*Hc + h)*64 + c0 + l31)) << 6) + kk*16 + hi*8;
        wh[kk] = *(const bf16x8*)(Wbh + woff);
        wl[kk] = *(const bf16x8*)(Wbl + woff);
    }
    float bias = Bs[(p*Hc + h)*64 + c0 + l31];
    f32x16 acc;
    #pragma unroll
    for (int i = 0; i < 16; ++i) acc[i] = bias;
    #pragma unroll
    for (int kk = 0; kk < 4; ++kk) {
        acc = mfma32bf(xh[kk], wh[kk], acc);
        acc = mfma32bf(xl[kk], wh[kk], acc);
        acc = mfma32bf(xh[kk], wl[kk], acc);
    }
    const int bh = b*Hc + h;
    if (p < 2) {
        _Float16* dst = (p == 0) ? Qf : Kf;
        #pragma unroll
        for (int r = 0; r < 16; ++r) {
            int row = (r & 3) + 8*(r >> 2) + 4*hi;
            size_t idx = (((size_t)bh*Nc + n0 + r0 + row) << 6) + c0 + l31;
            dst[idx] = (_Float16)acc[r];
        }
    } else {
        // V image granule (kb,o) = V[kb*8..+7][o], fp16, at tile offset 4096
        const int t_img = (n0 + r0) >> 5;
        char* img = (char*)KVimg + (size_t)(bh*96 + t_img)*TILEB;
        #pragma unroll
        for (int grp = 0; grp < 2; ++grp) {
            uint32_t wH[4];
            #pragma unroll
            for (int j = 0; j < 4; ++j)
                wH[j] = pkrtz(acc[grp*8 + 2*j], acc[grp*8 + 2*j + 1]);
            asm("v_permlane32_swap_b32 %0, %1" : "+v"(wH[0]), "+v"(wH[2]));
            asm("v_permlane32_swap_b32 %0, %1" : "+v"(wH[1]), "+v"(wH[3]));
            const int kb = grp*2 + hi;
            const int o  = c0 + l31;
            uint4 gh = {wH[0], wH[1], wH[2], wH[3]};
            *(uint4*)(img + 4096 + ((kb*64 + o) << 4)) = gh;
        }
    }
}

// ---- K image: granule (dc,key) = K[key][dc*8..+7] fp16, at tile offset 0 ----
__global__ void imgk_kernel(const _Float16* __restrict__ Kf, _Float16* __restrict__ KVimg)
{
    const int t = blockIdx.x % 96, bh = blockIdx.x / 96;
    char* img = (char*)KVimg + (size_t)(bh*96 + t)*TILEB;
    int dc = threadIdx.x & 7, key = threadIdx.x >> 3;
    size_t src = (((size_t)bh*Nc + t*32 + key) << 6) + dc*8;
    *(uint4*)(img + (dc*32 + key)*16) = *(const uint4*)(Kf + src);
}

// ---- flash attention fp16: 4 independent waves/block, KSC=8 -> 1536 blocks
//      (6 blocks/CU), K/V register-direct from KVimg granules (contiguous
//      1KB bursts), no LDS, no barriers. min-waves=3 keeps VGPR cap at 170. ----
__global__ __launch_bounds__(256, 3) void attn_mfma(
    const _Float16* __restrict__ Qf,
    const _Float16* __restrict__ KVimg, const uint32_t* __restrict__ pmT,
    float* __restrict__ PA, float* __restrict__ PL)
{
    const int lane = threadIdx.x & 63, w = threadIdx.x >> 6;  // w in [0,4)
    const int l31 = lane & 31, hi = lane >> 5;
    int gb = blockIdx.x;
    const int bh = gb & 7; gb >>= 3;        // XCD swizzle: one bh per XCD
    const int qt = gb % 24;
    const int ks = gb / 24;
    const int b = bh >> 2;
    const int qrow0 = qt*128 + w*32;
    const int t0 = ks*TPS;                  // in 32-key subtiles

    const uint32_t* pmp = pmT + ((size_t)b*NW32 + t0)*Nc + qrow0 + l31;
    const char* gt = (const char*)KVimg + (size_t)(bh*96 + t0)*TILEB;

    // Q B-frags (col = q-row = l31, k = d), pre-scaled by QSCALE, fp16
    f16x8 qf[4];
    #pragma unroll
    for (int kk = 0; kk < 4; ++kk) {
        size_t qoff = (((size_t)bh*Nc + qrow0 + l31) << 6) + kk*16 + hi*8;
        qf[kk] = *(const f16x8*)(Qf + qoff);
    }
    f32x16 fzero;
    #pragma unroll
    for (int i = 0; i < 16; ++i) fzero[i] = 0.f;
    const uint32_t ones32 = 0x3C003C00u;    // packed fp16 {1.0, 1.0}

    f32x16 acc0 = fzero, acc1 = fzero;
    float lsum = 0.f;

    // A/B register sets, prefetch-1 pipeline
    f16x8 KA[4], VA[4], KB[4], VB[4];
    uint32_t mwA, mwB;
    load_subtile(gt, hi, l31, KA, VA);
    mwA = pmp[0];

    #pragma unroll 1
    for (int j = 0; j < TPS/2; ++j) {       // 6 pair-iterations
        load_subtile(gt + (size_t)(2*j + 1)*TILEB, hi, l31, KB, VB);
        mwB = pmp[(size_t)(2*j + 1)*Nc];
        compute_subtile(KA, VA, mwA, hi, qf, fzero, ones32, acc0, acc1, lsum);
        const int tn = (2*j + 2 < TPS) ? (2*j + 2) : 0;   // tail clamp (unused)
        load_subtile(gt + (size_t)tn*TILEB, hi, l31, KA, VA);
        mwA = pmp[(size_t)tn*Nc];
        compute_subtile(KB, VB, mwB, hi, qf, fzero, ones32, acc0, acc1, lsum);
    }

    // ---- epilogue: PA[bh][ks][n][o], PL[bh][ks][n] ----
    lsum += __shfl_xor(lsum, 32);           // combine hi halves (16+16 keys)
    float* po = PA + (((size_t)(bh*KSC + ks)*Nc + qrow0) << 6);
    #pragma unroll
    for (int r = 0; r < 16; ++r) {
        int row = (r & 3) + 8*(r >> 2) + 4*hi;
        po[((size_t)row << 6) + l31]      = acc0[r];
        po[((size_t)row << 6) + 32 + l31] = acc1[r];
    }
    if (lane < 32)
        PL[(size_t)(bh*KSC + ks)*Nc + qrow0 + l31] = lsum;
}

// ---- merge: sum key-splits, divide, mean heads, leaky ----
__global__ void merge_kernel(const float* __restrict__ PA, const float* __restrict__ PL,
                             float* __restrict__ out)
{
    int gid = blockIdx.x*256 + threadIdx.x;
    int o  = gid & 63;
    int bn = gid >> 6;
    int n  = bn % Nc;
    int b  = bn / Nc;
    float ft = 0.f;
    for (int h = 0; h < Hc; ++h) {
        int bh = b*Hc + h;
        float A = 0.f, L = 0.f;
        for (int ks = 0; ks < KSC; ++ks) {
            A += PA[(((size_t)(bh*KSC + ks)*Nc + n) << 6) + o];
            L += PL[(size_t)(bh*KSC + ks)*Nc + n];
        }
        ft += A / L;
    }
    ft *= 0.25f;
    out[((size_t)bn << 6) + o] = fmaxf(ft, 0.f) + 0.2f*fminf(ft, 0.f);
}

extern "C" void kernel_launch(void* const* d_in, const int* in_sizes, int n_in,
                              void* d_out, int out_size, void* d_ws, size_t ws_size,
                              hipStream_t stream)
{
    const float* x    = (const float*)d_in[0];
    const int*   edge = (const int*)d_in[1];
    const float* Wv   = (const float*)d_in[2];
    const float* bv   = (const float*)d_in[3];
    const float* Wq   = (const float*)d_in[4];
    const float* bq   = (const float*)d_in[5];
    const float* Wk   = (const float*)d_in[6];
    const float* bk   = (const float*)d_in[7];
    float* out = (float*)d_out;

    const size_t PROJ = (size_t)Bc*Hc*Nc*64;
    char* p = (char*)d_ws;
    __bf16* Wbh = (__bf16*)p;     p += 49152*2;
    __bf16* Wbl = (__bf16*)p;     p += 49152*2;
    float*  Bs  = (float*)p;      p += 4096;
    _Float16* Qf = (_Float16*)p;  p += PROJ*2;
    _Float16* Kf = (_Float16*)p;  p += PROJ*2;
    _Float16* KVimg = (_Float16*)p; p += (size_t)Bc*Hc*96*TILEB;
    uint32_t* pmT = (uint32_t*)p; p += (size_t)Bc*NW32*Nc*4;
    float* PA = (float*)p;        p += (size_t)Bc*Hc*KSC*Nc*64*4;
    float* PL = (float*)p;

    hipLaunchKernelGGL(preppack_kernel, dim3(192 + Bc*NW32*48/4), dim3(256), 0, stream,
                       Wq, Wk, Wv, bq, bk, bv, edge, Wbh, Wbl, Bs, pmT);
    hipLaunchKernelGGL(qkv_mfma,    dim3(1152), dim3(256), 0, stream,
                       x, Wbh, Wbl, Bs, Qf, Kf, KVimg);
    hipLaunchKernelGGL(imgk_kernel, dim3(Bc*Hc*96), dim3(256), 0, stream, Kf, KVimg);
    hipLaunchKernelGGL(attn_mfma,   dim3(8*KSC*24), dim3(256), 0, stream,
                       Qf, KVimg, pmT, PA, PL);
    hipLaunchKernelGGL(merge_kernel, dim3((Bc*Nc*64)/256), dim3(256), 0, stream,
                       PA, PL, out);
}

// Round 18
// 74.562 us; speedup vs baseline: 1.7472x; 1.0576x over previous
//
#include <hip/hip_runtime.h>
#include <hip/hip_bf16.h>
#include <cstdint>

#define Bc 2
#define Nc 3072
#define Hc 4
#define NW32 96      // 32-key subtiles per row
#define TILEB 8192   // per 32-key fp16 image tile: K 4KB | V 4KB
#define KSC 4        // key splits -> grid 768
#define TPS (NW32/KSC)   // 24 subtiles per split

typedef __bf16    bf16x8 __attribute__((ext_vector_type(8)));
typedef _Float16  f16x8  __attribute__((ext_vector_type(8)));
typedef float     f32x16 __attribute__((ext_vector_type(16)));

#define QSCALE 0.18033688f   // 0.125 * log2(e): exp(s/8) == exp2(s*QSCALE)

static __device__ __forceinline__ f32x16 mfma32bf(bf16x8 a, bf16x8 b, f32x16 c) {
    return __builtin_amdgcn_mfma_f32_32x32x16_bf16(a, b, c, 0, 0, 0);
}
static __device__ __forceinline__ f32x16 mfma32h(f16x8 a, f16x8 b, f32x16 c) {
    return __builtin_amdgcn_mfma_f32_32x32x16_f16(a, b, c, 0, 0, 0);
}
static __device__ __forceinline__ uint32_t pkrtz(float lo, float hi) {
    uint32_t w;
    asm("v_cvt_pkrtz_f16_f32 %0, %1, %2" : "=v"(w) : "v"(lo), "v"(hi));
    return w;
}

// softmax for one 32-key subtile (16 scores/lane): leaky+exp2, pack to fp16,
// mask via sbfe (1-op sign spread) + bfi combine.  11 VALU ops per score-pair.
static __device__ __forceinline__ void softmax_pack(const f32x16& sc, uint32_t mwh,
                                                    uint32_t W8[8])
{
    #pragma unroll
    for (int i = 0; i < 8; ++i) {
        const int bp0 = (2*i & 3) + 8*(2*i >> 2);   // bp1 = bp0+1
        float s0 = sc[2*i], s1 = sc[2*i + 1];
        float a0 = fmaxf(s0, 0.2f*s0);
        float a1 = fmaxf(s1, 0.2f*s1);
        float e0, e1;
        asm("v_exp_f32 %0, %1" : "=v"(e0) : "v"(a0));   // exp2 (log2e pre-folded)
        asm("v_exp_f32 %0, %1" : "=v"(e1) : "v"(a1));
        uint32_t pk = pkrtz(e0, e1);
        uint32_t m0 = (uint32_t)__builtin_amdgcn_sbfe((int)mwh, bp0, 1);
        uint32_t m1 = (uint32_t)__builtin_amdgcn_sbfe((int)mwh, bp0 + 1, 1);
        uint32_t sel = (m0 & 0x0000ffffu) | (m1 & 0xffff0000u);   // v_bfi_b32
        W8[i] = pk & sel;
    }
}

static __device__ __forceinline__ void assemble_pa(uint32_t W8[8], f16x8& pa0, f16x8& pa1)
{
    uint32_t a0 = W8[0], a2 = W8[2], a1 = W8[1], a3 = W8[3];
    uint32_t b0 = W8[4], b2 = W8[6], b1 = W8[5], b3 = W8[7];
    asm("v_permlane32_swap_b32 %0, %1" : "+v"(a0), "+v"(a2));
    asm("v_permlane32_swap_b32 %0, %1" : "+v"(a1), "+v"(a3));
    asm("v_permlane32_swap_b32 %0, %1" : "+v"(b0), "+v"(b2));
    asm("v_permlane32_swap_b32 %0, %1" : "+v"(b1), "+v"(b3));
    union { uint32_t u[4]; f16x8 v; } u0, u1;
    u0.u[0] = a0; u0.u[1] = a1; u0.u[2] = a2; u0.u[3] = a3;
    u1.u[0] = b0; u1.u[1] = b1; u1.u[2] = b2; u1.u[3] = b3;
    pa0 = u0.v; pa1 = u1.v;
}

// load one subtile's K/V fragments from KVimg (granule layout, contiguous) to regs
static __device__ __forceinline__ void load_subtile(const char* gt, int hi, int l31,
                                                    f16x8 (&K)[4], f16x8 (&V)[4])
{
    #pragma unroll
    for (int kk = 0; kk < 4; ++kk)
        K[kk] = *(const f16x8*)(gt + ((kk*2 + hi) << 9) + (l31 << 4));
    #pragma unroll
    for (int i = 0; i < 4; ++i) {
        const int kkp = i >> 1, ot = i & 1;
        V[i] = *(const f16x8*)(gt + 4096 + ((kkp*2 + hi) << 10) + ((ot*32 + l31) << 4));
    }
}

// full compute for one subtile: QK^T (4 MFMA) -> softmax -> denom (2 ones-MFMA,
// idle MFMA pipe) + PV (4 MFMA)
static __device__ __forceinline__ void compute_subtile(
    const f16x8 (&K)[4], const f16x8 (&V)[4], uint32_t mw, int hi,
    const f16x8 (&qf)[4], const f32x16& fzero, const f16x8& ones,
    f32x16& acc0, f32x16& acc1, f32x16& acc2)
{
    f32x16 sc;
    __builtin_amdgcn_s_setprio(1);
    sc = mfma32h(K[0], qf[0], fzero);
    sc = mfma32h(K[1], qf[1], sc);
    sc = mfma32h(K[2], qf[2], sc);
    sc = mfma32h(K[3], qf[3], sc);
    __builtin_amdgcn_s_setprio(0);

    uint32_t W8[8];
    softmax_pack(sc, mw >> (hi*4), W8);
    f16x8 pa0, pa1;
    assemble_pa(W8, pa0, pa1);

    __builtin_amdgcn_s_setprio(1);
    acc2 = mfma32h(pa0, ones, acc2);
    acc2 = mfma32h(pa1, ones, acc2);
    acc0 = mfma32h(pa0, V[0], acc0);
    acc1 = mfma32h(pa0, V[1], acc1);
    acc0 = mfma32h(pa1, V[2], acc0);
    acc1 = mfma32h(pa1, V[3], acc1);
    __builtin_amdgcn_s_setprio(0);
}

// ---- fused prep + pack: blocks [0,192) convert W -> bf16 hi/lo (+bias);
//      blocks [192, 192+2304) bitpack adjacency transposed ----
__global__ void preppack_kernel(const float* __restrict__ Wq, const float* __restrict__ Wk,
                                const float* __restrict__ Wv,
                                const float* __restrict__ bq, const float* __restrict__ bk,
                                const float* __restrict__ bv,
                                const int* __restrict__ edge,
                                __bf16* __restrict__ Wbh, __bf16* __restrict__ Wbl,
                                float* __restrict__ Bs, uint32_t* __restrict__ pmT)
{
    if (blockIdx.x < 192) {
        int i = blockIdx.x*256 + threadIdx.x;   // 49152
        int d = i & 63, o = (i >> 6) & 63, h = (i >> 12) & 3, p = i >> 14;
        const float* W = (p == 0) ? Wq : (p == 1) ? Wk : Wv;
        float scale = (p == 0) ? QSCALE : 1.0f;
        float val = W[(h*64 + d)*64 + o] * scale;
        int idx = (((p*Hc + h)*64 + o) << 6) + d;
        __bf16 hi = (__bf16)val;
        Wbh[idx] = hi;
        Wbl[idx] = (__bf16)(val - (float)hi);
        if (i < 3*Hc*64) {
            int pp = i / (Hc*64), rest = i % (Hc*64);
            const float* B = (pp == 0) ? bq : (pp == 1) ? bk : bv;
            Bs[i] = B[rest] * ((pp == 0) ? QSCALE : 1.0f);
        }
    } else {
        int gw = (blockIdx.x - 192)*4 + (threadIdx.x >> 6);
        int lane = threadIdx.x & 63;
        int ng = gw % 48; gw /= 48;
        int w  = gw % NW32; gw /= NW32;
        int b  = gw;
        int n = ng*64 + lane;
        const uint4* ep = (const uint4*)(edge + ((size_t)b*Nc + n)*Nc + w*32);
        uint32_t word = 0;
        #pragma unroll
        for (int i = 0; i < 8; ++i) {
            uint4 e = ep[i];
            word |= (e.x ? 1u : 0u) << (4*i);
            word |= (e.y ? 1u : 0u) << (4*i + 1);
            word |= (e.z ? 1u : 0u) << (4*i + 2);
            word |= (e.w ? 1u : 0u) << (4*i + 3);
        }
        pmT[((size_t)b*NW32 + w)*Nc + n] = word;
    }
}

// ---- QKV projection via MFMA (split-bf16, x converted in-register).
//      Q,K -> fp16 flat [bh][n][64]; V -> KVimg granules (tile offset 4096) ----
__global__ __launch_bounds__(256) void qkv_mfma(
    const float* __restrict__ x,
    const __bf16* __restrict__ Wbh, const __bf16* __restrict__ Wbl,
    const float* __restrict__ Bs,
    _Float16* __restrict__ Qf, _Float16* __restrict__ Kf,
    _Float16* __restrict__ KVimg)
{
    const int lane = threadIdx.x & 63, w = threadIdx.x >> 6;
    const int l31 = lane & 31, hi = lane >> 5;
    int t = blockIdx.x;                 // 1152 blocks
    int nt = t % 48; t /= 48;
    int b  = t & 1;  t >>= 1;
    int p  = t % 3;
    int h  = t / 3;
    const int r0 = (w >> 1)*32, c0 = (w & 1)*32, n0 = nt*64;

    bf16x8 xh[4], xl[4], wh[4], wl[4];
    #pragma unroll
    for (int kk = 0; kk < 4; ++kk) {
        size_t xoff = (((size_t)(b*Nc + n0 + r0 + l31)) << 6) + kk*16 + hi*8;
        float4 f0 = *(const float4*)(x + xoff);
        float4 f1 = *(const float4*)(x + xoff + 4);
        float xs[8] = {f0.x, f0.y, f0.z, f0.w, f1.x, f1.y, f1.z, f1.w};
        #pragma unroll
        for (int j = 0; j < 8; ++j) {
            __bf16 hh = (__bf16)xs[j];
            xh[kk][j] = hh;
            xl[kk][j] = (__bf16)(xs[j] - (float)hh);
        }
        size_t woff = (((size_t)((p*Hc + h)*64 + c0 + l31)) << 6) + kk*16 + hi*8;
        wh[kk] = *(const bf16x8*)(Wbh + woff);
        wl[kk] = *(const bf16x8*)(Wbl + woff);
    }
    float bias = Bs[(p*Hc + h)*64 + c0 + l31];
    f32x16 acc;
    #pragma unroll
    for (int i = 0; i < 16; ++i) acc[i] = bias;
    #pragma unroll
    for (int kk = 0; kk < 4; ++kk) {
        acc = mfma32bf(xh[kk], wh[kk], acc);
        acc = mfma32bf(xl[kk], wh[kk], acc);
        acc = mfma32bf(xh[kk], wl[kk], acc);
    }
    const int bh = b*Hc + h;
    if (p < 2) {
        _Float16* dst = (p == 0) ? Qf : Kf;
        #pragma unroll
        for (int r = 0; r < 16; ++r) {
            int row = (r & 3) + 8*(r >> 2) + 4*hi;
            size_t idx = (((size_t)bh*Nc + n0 + r0 + row) << 6) + c0 + l31;
            dst[idx] = (_Float16)acc[r];
        }
    } else {
        // V image granule (kb,o) = V[kb*8..+7][o], fp16, at tile offset 4096
        const int t_img = (n0 + r0) >> 5;
        char* img = (char*)KVimg + (size_t)(bh*96 + t_img)*TILEB;
        #pragma unroll
        for (int grp = 0; grp < 2; ++grp) {
            uint32_t wH[4];
            #pragma unroll
            for (int j = 0; j < 4; ++j)
                wH[j] = pkrtz(acc[grp*8 + 2*j], acc[grp*8 + 2*j + 1]);
            asm("v_permlane32_swap_b32 %0, %1" : "+v"(wH[0]), "+v"(wH[2]));
            asm("v_permlane32_swap_b32 %0, %1" : "+v"(wH[1]), "+v"(wH[3]));
            const int kb = grp*2 + hi;
            const int o  = c0 + l31;
            uint4 gh = {wH[0], wH[1], wH[2], wH[3]};
            *(uint4*)(img + 4096 + ((kb*64 + o) << 4)) = gh;
        }
    }
}

// ---- K image: granule (dc,key) = K[key][dc*8..+7] fp16, at tile offset 0 ----
__global__ void imgk_kernel(const _Float16* __restrict__ Kf, _Float16* __restrict__ KVimg)
{
    const int t = blockIdx.x % 96, bh = blockIdx.x / 96;
    char* img = (char*)KVimg + (size_t)(bh*96 + t)*TILEB;
    int dc = threadIdx.x & 7, key = threadIdx.x >> 3;
    size_t src = (((size_t)bh*Nc + t*32 + key) << 6) + dc*8;
    *(uint4*)(img + (dc*32 + key)*16) = *(const uint4*)(Kf + src);
}

// ---- flash attention fp16: 4 independent waves/block, register-direct KVimg
//      reads (contiguous 1KB bursts), no LDS, no barriers. Denominator on the
//      MFMA pipe (ones-MFMA into acc2). ----
__global__ __launch_bounds__(256, 3) void attn_mfma(
    const _Float16* __restrict__ Qf,
    const _Float16* __restrict__ KVimg, const uint32_t* __restrict__ pmT,
    float* __restrict__ PA, float* __restrict__ PL)
{
    const int lane = threadIdx.x & 63, w = threadIdx.x >> 6;  // w in [0,4)
    const int l31 = lane & 31, hi = lane >> 5;
    int gb = blockIdx.x;
    const int bh = gb & 7; gb >>= 3;        // XCD swizzle: one bh per XCD
    const int qt = gb % 24;
    const int ks = gb / 24;
    const int b = bh >> 2;
    const int qrow0 = qt*128 + w*32;
    const int t0 = ks*TPS;                  // in 32-key subtiles

    const uint32_t* pmp = pmT + ((size_t)b*NW32 + t0)*Nc + qrow0 + l31;
    const char* gt = (const char*)KVimg + (size_t)(bh*96 + t0)*TILEB;

    // Q B-frags (col = q-row = l31, k = d), pre-scaled by QSCALE, fp16
    f16x8 qf[4];
    #pragma unroll
    for (int kk = 0; kk < 4; ++kk) {
        size_t qoff = (((size_t)bh*Nc + qrow0 + l31) << 6) + kk*16 + hi*8;
        qf[kk] = *(const f16x8*)(Qf + qoff);
    }
    f32x16 fzero;
    #pragma unroll
    for (int i = 0; i < 16; ++i) fzero[i] = 0.f;
    f16x8 ones;
    #pragma unroll
    for (int j = 0; j < 8; ++j) ones[j] = (_Float16)1.0f;

    f32x16 acc0 = fzero, acc1 = fzero, acc2 = fzero;

    // A/B register sets, prefetch-1 pipeline
    f16x8 KA[4], VA[4], KB[4], VB[4];
    uint32_t mwA, mwB;
    load_subtile(gt, hi, l31, KA, VA);
    mwA = pmp[0];

    #pragma unroll 1
    for (int j = 0; j < TPS/2; ++j) {       // 12 pair-iterations
        load_subtile(gt + (size_t)(2*j + 1)*TILEB, hi, l31, KB, VB);
        mwB = pmp[(size_t)(2*j + 1)*Nc];
        compute_subtile(KA, VA, mwA, hi, qf, fzero, ones, acc0, acc1, acc2);
        const int tn = (2*j + 2 < TPS) ? (2*j + 2) : 0;   // tail clamp (unused)
        load_subtile(gt + (size_t)tn*TILEB, hi, l31, KA, VA);
        mwA = pmp[(size_t)tn*Nc];
        compute_subtile(KB, VB, mwB, hi, qf, fzero, ones, acc0, acc1, acc2);
    }

    // ---- epilogue: PA[bh][ks][n][o], PL[bh][ks][n] (rowsums in acc2) ----
    float* po = PA + (((size_t)(bh*KSC + ks)*Nc + qrow0) << 6);
    #pragma unroll
    for (int r = 0; r < 16; ++r) {
        int row = (r & 3) + 8*(r >> 2) + 4*hi;
        po[((size_t)row << 6) + l31]      = acc0[r];
        po[((size_t)row << 6) + 32 + l31] = acc1[r];
    }
    if (l31 == 0) {
        float* pl = PL + (size_t)(bh*KSC + ks)*Nc + qrow0;
        #pragma unroll
        for (int r = 0; r < 16; ++r)
            pl[(r & 3) + 8*(r >> 2) + 4*hi] = acc2[r];
    }
}

// ---- merge: sum key-splits, divide, mean heads, leaky ----
__global__ void merge_kernel(const float* __restrict__ PA, const float* __restrict__ PL,
                             float* __restrict__ out)
{
    int gid = blockIdx.x*256 + threadIdx.x;
    int o  = gid & 63;
    int bn = gid >> 6;
    int n  = bn % Nc;
    int b  = bn / Nc;
    float ft = 0.f;
    for (int h = 0; h < Hc; ++h) {
        int bh = b*Hc + h;
        float A = 0.f, L = 0.f;
        for (int ks = 0; ks < KSC; ++ks) {
            A += PA[(((size_t)(bh*KSC + ks)*Nc + n) << 6) + o];
            L += PL[(size_t)(bh*KSC + ks)*Nc + n];
        }
        ft += A / L;
    }
    ft *= 0.25f;
    out[((size_t)bn << 6) + o] = fmaxf(ft, 0.f) + 0.2f*fminf(ft, 0.f);
}

extern "C" void kernel_launch(void* const* d_in, const int* in_sizes, int n_in,
                              void* d_out, int out_size, void* d_ws, size_t ws_size,
                              hipStream_t stream)
{
    const float* x    = (const float*)d_in[0];
    const int*   edge = (const int*)d_in[1];
    const float* Wv   = (const float*)d_in[2];
    const float* bv   = (const float*)d_in[3];
    const float* Wq   = (const float*)d_in[4];
    const float* bq   = (const float*)d_in[5];
    const float* Wk   = (const float*)d_in[6];
    const float* bk   = (const float*)d_in[7];
    float* out = (float*)d_out;

    const size_t PROJ = (size_t)Bc*Hc*Nc*64;
    char* p = (char*)d_ws;
    __bf16* Wbh = (__bf16*)p;     p += 49152*2;
    __bf16* Wbl = (__bf16*)p;     p += 49152*2;
    float*  Bs  = (float*)p;      p += 4096;
    _Float16* Qf = (_Float16*)p;  p += PROJ*2;
    _Float16* Kf = (_Float16*)p;  p += PROJ*2;
    _Float16* KVimg = (_Float16*)p; p += (size_t)Bc*Hc*96*TILEB;
    uint32_t* pmT = (uint32_t*)p; p += (size_t)Bc*NW32*Nc*4;
    float* PA = (float*)p;        p += (size_t)Bc*Hc*KSC*Nc*64*4;
    float* PL = (float*)p;

    hipLaunchKernelGGL(preppack_kernel, dim3(192 + Bc*NW32*48/4), dim3(256), 0, stream,
                       Wq, Wk, Wv, bq, bk, bv, edge, Wbh, Wbl, Bs, pmT);
    hipLaunchKernelGGL(qkv_mfma,    dim3(1152), dim3(256), 0, stream,
                       x, Wbh, Wbl, Bs, Qf, Kf, KVimg);
    hipLaunchKernelGGL(imgk_kernel, dim3(Bc*Hc*96), dim3(256), 0, stream, Kf, KVimg);
    hipLaunchKernelGGL(attn_mfma,   dim3(8*KSC*24), dim3(256), 0, stream,
                       Qf, KVimg, pmT, PA, PL);
    hipLaunchKernelGGL(merge_kernel, dim3((Bc*Nc*64)/256), dim3(256), 0, stream,
                       PA, PL, out);
}

// Round 19
// 72.264 us; speedup vs baseline: 1.8028x; 1.0318x over previous
//
#include <hip/hip_runtime.h>
#include <hip/hip_bf16.h>
#include <cstdint>

#define Bc 2
#define Nc 3072
#define Hc 4
#define NW32 96      // 32-key subtiles per row
#define TILEB 8192   // per 32-key fp16 image tile: K 4KB | V 4KB
#define KSC 4        // key splits -> grid 768
#define TPS (NW32/KSC)   // 24 subtiles per split

typedef __bf16    bf16x8 __attribute__((ext_vector_type(8)));
typedef _Float16  f16x8  __attribute__((ext_vector_type(8)));
typedef _Float16  f16x4  __attribute__((ext_vector_type(4)));
typedef float     f32x16 __attribute__((ext_vector_type(16)));

#define QSCALE 0.18033688f   // 0.125 * log2(e): exp(s/8) == exp2(s*QSCALE)

static __device__ __forceinline__ f32x16 mfma32bf(bf16x8 a, bf16x8 b, f32x16 c) {
    return __builtin_amdgcn_mfma_f32_32x32x16_bf16(a, b, c, 0, 0, 0);
}
static __device__ __forceinline__ f32x16 mfma32h(f16x8 a, f16x8 b, f32x16 c) {
    return __builtin_amdgcn_mfma_f32_32x32x16_f16(a, b, c, 0, 0, 0);
}
static __device__ __forceinline__ uint32_t pkrtz(float lo, float hi) {
    uint32_t w;
    asm("v_cvt_pkrtz_f16_f32 %0, %1, %2" : "=v"(w) : "v"(lo), "v"(hi));
    return w;
}

// softmax for one 32-key subtile (16 scores/lane): leaky+exp2, pack to fp16,
// mask via sbfe (1-op sign spread) + bfi combine.
static __device__ __forceinline__ void softmax_pack(const f32x16& sc, uint32_t mwh,
                                                    uint32_t W8[8])
{
    #pragma unroll
    for (int i = 0; i < 8; ++i) {
        const int bp0 = (2*i & 3) + 8*(2*i >> 2);   // bp1 = bp0+1
        float s0 = sc[2*i], s1 = sc[2*i + 1];
        float a0 = fmaxf(s0, 0.2f*s0);
        float a1 = fmaxf(s1, 0.2f*s1);
        float e0, e1;
        asm("v_exp_f32 %0, %1" : "=v"(e0) : "v"(a0));   // exp2 (log2e pre-folded)
        asm("v_exp_f32 %0, %1" : "=v"(e1) : "v"(a1));
        uint32_t pk = pkrtz(e0, e1);
        uint32_t m0 = (uint32_t)__builtin_amdgcn_sbfe((int)mwh, bp0, 1);
        uint32_t m1 = (uint32_t)__builtin_amdgcn_sbfe((int)mwh, bp0 + 1, 1);
        uint32_t sel = (m0 & 0x0000ffffu) | (m1 & 0xffff0000u);   // v_bfi_b32
        W8[i] = pk & sel;
    }
}

static __device__ __forceinline__ void assemble_pa(uint32_t W8[8], f16x8& pa0, f16x8& pa1)
{
    uint32_t a0 = W8[0], a2 = W8[2], a1 = W8[1], a3 = W8[3];
    uint32_t b0 = W8[4], b2 = W8[6], b1 = W8[5], b3 = W8[7];
    asm("v_permlane32_swap_b32 %0, %1" : "+v"(a0), "+v"(a2));
    asm("v_permlane32_swap_b32 %0, %1" : "+v"(a1), "+v"(a3));
    asm("v_permlane32_swap_b32 %0, %1" : "+v"(b0), "+v"(b2));
    asm("v_permlane32_swap_b32 %0, %1" : "+v"(b1), "+v"(b3));
    union { uint32_t u[4]; f16x8 v; } u0, u1;
    u0.u[0] = a0; u0.u[1] = a1; u0.u[2] = a2; u0.u[3] = a3;
    u1.u[0] = b0; u1.u[1] = b1; u1.u[2] = b2; u1.u[3] = b3;
    pa0 = u0.v; pa1 = u1.v;
}

// load one subtile's K/V fragments from KVimg (granule layout, contiguous) to regs
static __device__ __forceinline__ void load_subtile(const char* gt, int hi, int l31,
                                                    f16x8 (&K)[4], f16x8 (&V)[4])
{
    #pragma unroll
    for (int kk = 0; kk < 4; ++kk)
        K[kk] = *(const f16x8*)(gt + ((kk*2 + hi) << 9) + (l31 << 4));
    #pragma unroll
    for (int i = 0; i < 4; ++i) {
        const int kkp = i >> 1, ot = i & 1;
        V[i] = *(const f16x8*)(gt + 4096 + ((kkp*2 + hi) << 10) + ((ot*32 + l31) << 4));
    }
}

// full compute for one subtile: QK^T (4 MFMA) -> softmax -> denom (2 ones-MFMA)
// + PV (4 MFMA)
static __device__ __forceinline__ void compute_subtile(
    const f16x8 (&K)[4], const f16x8 (&V)[4], uint32_t mw, int hi,
    const f16x8 (&qf)[4], const f32x16& fzero, const f16x8& ones,
    f32x16& acc0, f32x16& acc1, f32x16& acc2)
{
    f32x16 sc;
    __builtin_amdgcn_s_setprio(1);
    sc = mfma32h(K[0], qf[0], fzero);
    sc = mfma32h(K[1], qf[1], sc);
    sc = mfma32h(K[2], qf[2], sc);
    sc = mfma32h(K[3], qf[3], sc);
    __builtin_amdgcn_s_setprio(0);

    uint32_t W8[8];
    softmax_pack(sc, mw >> (hi*4), W8);
    f16x8 pa0, pa1;
    assemble_pa(W8, pa0, pa1);

    __builtin_amdgcn_s_setprio(1);
    acc2 = mfma32h(pa0, ones, acc2);
    acc2 = mfma32h(pa1, ones, acc2);
    acc0 = mfma32h(pa0, V[0], acc0);
    acc1 = mfma32h(pa0, V[1], acc1);
    acc0 = mfma32h(pa1, V[2], acc0);
    acc1 = mfma32h(pa1, V[3], acc1);
    __builtin_amdgcn_s_setprio(0);
}

// ---- fused prep + pack ----
__global__ void preppack_kernel(const float* __restrict__ Wq, const float* __restrict__ Wk,
                                const float* __restrict__ Wv,
                                const float* __restrict__ bq, const float* __restrict__ bk,
                                const float* __restrict__ bv,
                                const int* __restrict__ edge,
                                __bf16* __restrict__ Wbh, __bf16* __restrict__ Wbl,
                                float* __restrict__ Bs, uint32_t* __restrict__ pmT)
{
    if (blockIdx.x < 192) {
        int i = blockIdx.x*256 + threadIdx.x;   // 49152
        int d = i & 63, o = (i >> 6) & 63, h = (i >> 12) & 3, p = i >> 14;
        const float* W = (p == 0) ? Wq : (p == 1) ? Wk : Wv;
        float scale = (p == 0) ? QSCALE : 1.0f;
        float val = W[(h*64 + d)*64 + o] * scale;
        int idx = (((p*Hc + h)*64 + o) << 6) + d;
        __bf16 hi = (__bf16)val;
        Wbh[idx] = hi;
        Wbl[idx] = (__bf16)(val - (float)hi);
        if (i < 3*Hc*64) {
            int pp = i / (Hc*64), rest = i % (Hc*64);
            const float* B = (pp == 0) ? bq : (pp == 1) ? bk : bv;
            Bs[i] = B[rest] * ((pp == 0) ? QSCALE : 1.0f);
        }
    } else {
        int gw = (blockIdx.x - 192)*4 + (threadIdx.x >> 6);
        int lane = threadIdx.x & 63;
        int ng = gw % 48; gw /= 48;
        int w  = gw % NW32; gw /= NW32;
        int b  = gw;
        int n = ng*64 + lane;
        const uint4* ep = (const uint4*)(edge + ((size_t)b*Nc + n)*Nc + w*32);
        uint32_t word = 0;
        #pragma unroll
        for (int i = 0; i < 8; ++i) {
            uint4 e = ep[i];
            word |= (e.x ? 1u : 0u) << (4*i);
            word |= (e.y ? 1u : 0u) << (4*i + 1);
            word |= (e.z ? 1u : 0u) << (4*i + 2);
            word |= (e.w ? 1u : 0u) << (4*i + 3);
        }
        pmT[((size_t)b*NW32 + w)*Nc + n] = word;
    }
}

// ---- QKV projection via MFMA (split-bf16, x converted in-register) ----
__global__ __launch_bounds__(256) void qkv_mfma(
    const float* __restrict__ x,
    const __bf16* __restrict__ Wbh, const __bf16* __restrict__ Wbl,
    const float* __restrict__ Bs,
    _Float16* __restrict__ Qf, _Float16* __restrict__ Kf,
    _Float16* __restrict__ KVimg)
{
    const int lane = threadIdx.x & 63, w = threadIdx.x >> 6;
    const int l31 = lane & 31, hi = lane >> 5;
    int t = blockIdx.x;                 // 1152 blocks
    int nt = t % 48; t /= 48;
    int b  = t & 1;  t >>= 1;
    int p  = t % 3;
    int h  = t / 3;
    const int r0 = (w >> 1)*32, c0 = (w & 1)*32, n0 = nt*64;

    bf16x8 xh[4], xl[4], wh[4], wl[4];
    #pragma unroll
    for (int kk = 0; kk < 4; ++kk) {
        size_t xoff = (((size_t)(b*Nc + n0 + r0 + l31)) << 6) + kk*16 + hi*8;
        float4 f0 = *(const float4*)(x + xoff);
        float4 f1 = *(const float4*)(x + xoff + 4);
        float xs[8] = {f0.x, f0.y, f0.z, f0.w, f1.x, f1.y, f1.z, f1.w};
        #pragma unroll
        for (int j = 0; j < 8; ++j) {
            __bf16 hh = (__bf16)xs[j];
            xh[kk][j] = hh;
            xl[kk][j] = (__bf16)(xs[j] - (float)hh);
        }
        size_t woff = (((size_t)((p*Hc + h)*64 + c0 + l31)) << 6) + kk*16 + hi*8;
        wh[kk] = *(const bf16x8*)(Wbh + woff);
        wl[kk] = *(const bf16x8*)(Wbl + woff);
    }
    float bias = Bs[(p*Hc + h)*64 + c0 + l31];
    f32x16 acc;
    #pragma unroll
    for (int i = 0; i < 16; ++i) acc[i] = bias;
    #pragma unroll
    for (int kk = 0; kk < 4; ++kk) {
        acc = mfma32bf(xh[kk], wh[kk], acc);
        acc = mfma32bf(xl[kk], wh[kk], acc);
        acc = mfma32bf(xh[kk], wl[kk], acc);
    }
    const int bh = b*Hc + h;
    if (p < 2) {
        _Float16* dst = (p == 0) ? Qf : Kf;
        #pragma unroll
        for (int r = 0; r < 16; ++r) {
            int row = (r & 3) + 8*(r >> 2) + 4*hi;
            size_t idx = (((size_t)bh*Nc + n0 + r0 + row) << 6) + c0 + l31;
            dst[idx] = (_Float16)acc[r];
        }
    } else {
        // V image granule (kb,o) = V[kb*8..+7][o], fp16, at tile offset 4096
        const int t_img = (n0 + r0) >> 5;
        char* img = (char*)KVimg + (size_t)(bh*96 + t_img)*TILEB;
        #pragma unroll
        for (int grp = 0; grp < 2; ++grp) {
            uint32_t wH[4];
            #pragma unroll
            for (int j = 0; j < 4; ++j)
                wH[j] = pkrtz(acc[grp*8 + 2*j], acc[grp*8 + 2*j + 1]);
            asm("v_permlane32_swap_b32 %0, %1" : "+v"(wH[0]), "+v"(wH[2]));
            asm("v_permlane32_swap_b32 %0, %1" : "+v"(wH[1]), "+v"(wH[3]));
            const int kb = grp*2 + hi;
            const int o  = c0 + l31;
            uint4 gh = {wH[0], wH[1], wH[2], wH[3]};
            *(uint4*)(img + 4096 + ((kb*64 + o) << 4)) = gh;
        }
    }
}

// ---- K image: granule (dc,key) = K[key][dc*8..+7] fp16, at tile offset 0 ----
__global__ void imgk_kernel(const _Float16* __restrict__ Kf, _Float16* __restrict__ KVimg)
{
    const int t = blockIdx.x % 96, bh = blockIdx.x / 96;
    char* img = (char*)KVimg + (size_t)(bh*96 + t)*TILEB;
    int dc = threadIdx.x & 7, key = threadIdx.x >> 3;
    size_t src = (((size_t)bh*Nc + t*32 + key) << 6) + dc*8;
    *(uint4*)(img + (dc*32 + key)*16) = *(const uint4*)(Kf + src);
}

// ---- flash attention fp16: register-direct KVimg reads, no LDS, no barriers.
//      Partials stored in fp16 (halves epilogue + merge traffic). ----
__global__ __launch_bounds__(256, 3) void attn_mfma(
    const _Float16* __restrict__ Qf,
    const _Float16* __restrict__ KVimg, const uint32_t* __restrict__ pmT,
    _Float16* __restrict__ PAh, float* __restrict__ PL)
{
    const int lane = threadIdx.x & 63, w = threadIdx.x >> 6;  // w in [0,4)
    const int l31 = lane & 31, hi = lane >> 5;
    int gb = blockIdx.x;
    const int bh = gb & 7; gb >>= 3;        // XCD swizzle: one bh per XCD
    const int qt = gb % 24;
    const int ks = gb / 24;
    const int b = bh >> 2;
    const int qrow0 = qt*128 + w*32;
    const int t0 = ks*TPS;                  // in 32-key subtiles

    const uint32_t* pmp = pmT + ((size_t)b*NW32 + t0)*Nc + qrow0 + l31;
    const char* gt = (const char*)KVimg + (size_t)(bh*96 + t0)*TILEB;

    // Q B-frags (col = q-row = l31, k = d), pre-scaled by QSCALE, fp16
    f16x8 qf[4];
    #pragma unroll
    for (int kk = 0; kk < 4; ++kk) {
        size_t qoff = (((size_t)bh*Nc + qrow0 + l31) << 6) + kk*16 + hi*8;
        qf[kk] = *(const f16x8*)(Qf + qoff);
    }
    f32x16 fzero;
    #pragma unroll
    for (int i = 0; i < 16; ++i) fzero[i] = 0.f;
    f16x8 ones;
    #pragma unroll
    for (int j = 0; j < 8; ++j) ones[j] = (_Float16)1.0f;

    f32x16 acc0 = fzero, acc1 = fzero, acc2 = fzero;

    // A/B register sets, prefetch-1 pipeline
    f16x8 KA[4], VA[4], KB[4], VB[4];
    uint32_t mwA, mwB;
    load_subtile(gt, hi, l31, KA, VA);
    mwA = pmp[0];

    #pragma unroll 1
    for (int j = 0; j < TPS/2; ++j) {       // 12 pair-iterations
        load_subtile(gt + (size_t)(2*j + 1)*TILEB, hi, l31, KB, VB);
        mwB = pmp[(size_t)(2*j + 1)*Nc];
        compute_subtile(KA, VA, mwA, hi, qf, fzero, ones, acc0, acc1, acc2);
        const int tn = (2*j + 2 < TPS) ? (2*j + 2) : 0;   // tail clamp (unused)
        load_subtile(gt + (size_t)tn*TILEB, hi, l31, KA, VA);
        mwA = pmp[(size_t)tn*Nc];
        compute_subtile(KB, VB, mwB, hi, qf, fzero, ones, acc0, acc1, acc2);
    }

    // ---- epilogue: PAh[bh][ks][n][o] fp16, PL[bh][ks][n] (rowsums in acc2) ----
    _Float16* po = PAh + (((size_t)(bh*KSC + ks)*Nc + qrow0) << 6);
    #pragma unroll
    for (int r = 0; r < 16; ++r) {
        int row = (r & 3) + 8*(r >> 2) + 4*hi;
        po[((size_t)row << 6) + l31]      = (_Float16)acc0[r];
        po[((size_t)row << 6) + 32 + l31] = (_Float16)acc1[r];
    }
    if (l31 == 0) {
        float* pl = PL + (size_t)(bh*KSC + ks)*Nc + qrow0;
        #pragma unroll
        for (int r = 0; r < 16; ++r)
            pl[(r & 3) + 8*(r >> 2) + 4*hi] = acc2[r];
    }
}

// ---- merge (vectorized x4): sum key-splits, divide, mean heads, leaky ----
__global__ void merge_kernel(const _Float16* __restrict__ PAh,
                             const float* __restrict__ PL, float* __restrict__ out)
{
    int gid = blockIdx.x*256 + threadIdx.x;   // B*N*16 threads
    int og = (gid & 15) << 2;                 // o group of 4
    int bn = gid >> 4;
    int n  = bn % Nc;
    int b  = bn / Nc;
    float f0 = 0.f, f1 = 0.f, f2 = 0.f, f3 = 0.f;
    for (int h = 0; h < Hc; ++h) {
        int bh = b*Hc + h;
        float A0 = 0.f, A1 = 0.f, A2 = 0.f, A3 = 0.f, L = 0.f;
        for (int ks = 0; ks < KSC; ++ks) {
            size_t base = ((size_t)(bh*KSC + ks)*Nc + n);
            f16x4 a = *(const f16x4*)(PAh + (base << 6) + og);
            A0 += (float)a[0]; A1 += (float)a[1];
            A2 += (float)a[2]; A3 += (float)a[3];
            L  += PL[base];
        }
        float invL = 1.0f / L;
        f0 += A0*invL; f1 += A1*invL; f2 += A2*invL; f3 += A3*invL;
    }
    float4 r;
    r.x = f0*0.25f; r.y = f1*0.25f; r.z = f2*0.25f; r.w = f3*0.25f;
    r.x = fmaxf(r.x, 0.f) + 0.2f*fminf(r.x, 0.f);
    r.y = fmaxf(r.y, 0.f) + 0.2f*fminf(r.y, 0.f);
    r.z = fmaxf(r.z, 0.f) + 0.2f*fminf(r.z, 0.f);
    r.w = fmaxf(r.w, 0.f) + 0.2f*fminf(r.w, 0.f);
    *(float4*)(out + ((size_t)bn << 6) + og) = r;
}

extern "C" void kernel_launch(void* const* d_in, const int* in_sizes, int n_in,
                              void* d_out, int out_size, void* d_ws, size_t ws_size,
                              hipStream_t stream)
{
    const float* x    = (const float*)d_in[0];
    const int*   edge = (const int*)d_in[1];
    const float* Wv   = (const float*)d_in[2];
    const float* bv   = (const float*)d_in[3];
    const float* Wq   = (const float*)d_in[4];
    const float* bq   = (const float*)d_in[5];
    const float* Wk   = (const float*)d_in[6];
    const float* bk   = (const float*)d_in[7];
    float* out = (float*)d_out;

    const size_t PROJ = (size_t)Bc*Hc*Nc*64;
    char* p = (char*)d_ws;
    __bf16* Wbh = (__bf16*)p;     p += 49152*2;
    __bf16* Wbl = (__bf16*)p;     p += 49152*2;
    float*  Bs  = (float*)p;      p += 4096;
    _Float16* Qf = (_Float16*)p;  p += PROJ*2;
    _Float16* Kf = (_Float16*)p;  p += PROJ*2;
    _Float16* KVimg = (_Float16*)p; p += (size_t)Bc*Hc*96*TILEB;
    uint32_t* pmT = (uint32_t*)p; p += (size_t)Bc*NW32*Nc*4;
    _Float16* PAh = (_Float16*)p; p += (size_t)Bc*Hc*KSC*Nc*64*2;
    float* PL = (float*)p;

    hipLaunchKernelGGL(preppack_kernel, dim3(192 + Bc*NW32*48/4), dim3(256), 0, stream,
                       Wq, Wk, Wv, bq, bk, bv, edge, Wbh, Wbl, Bs, pmT);
    hipLaunchKernelGGL(qkv_mfma,    dim3(1152), dim3(256), 0, stream,
                       x, Wbh, Wbl, Bs, Qf, Kf, KVimg);
    hipLaunchKernelGGL(imgk_kernel, dim3(Bc*Hc*96), dim3(256), 0, stream, Kf, KVimg);
    hipLaunchKernelGGL(attn_mfma,   dim3(8*KSC*24), dim3(256), 0, stream,
                       Qf, KVimg, pmT, PAh, PL);
    hipLaunchKernelGGL(merge_kernel, dim3((Bc*Nc*16)/256), dim3(256), 0, stream,
                       PAh, PL, out);
}